// Round 11
// baseline (3734.030 us; speedup 1.0000x reference)
//
#include <hip/hip_runtime.h>
#include <math.h>

// GraphEncoder v8 = v7 (passed, 1747us) + two phase optimizations:
//  1. Epilogue (leaky -> @W -> tanh*q -> k-softmax) moved OUT of the wave-serial
//     phase tail INTO thread-per-row ego (dense FMA loops, 64 rows/wave).
//     Phase now stores the raw attention aggregate z_agg = acc/ssum only;
//     the r array is gone (computed in-register by ego).
//  2. t-loop unroll 4 -> 4 outstanding row-gathers/wave (halve latency stall).

#define KF 2
#define DK 25
#define DD 50
#define PS 52   // padded P row stride: 208 B = 13 float4
#define ITERS 4
#define WPB 4

static __device__ __forceinline__ float leakyf(float x) { return x > 0.f ? x : 0.2f * x; }

// at[e] is [2][50]: factor k at a+k*50; 0..24 row-side, 25..49 col-side.
static __device__ __forceinline__ float2 score_row50(const float* p, const float* a) {
    float s0 = 0.f, s1 = 0.f;
    #pragma unroll
    for (int f = 0; f < DK; ++f) {
        s0 = fmaf(p[f],      a[f],      s0);
        s1 = fmaf(p[DK + f], a[50 + f], s1);
    }
    return make_float2(s0, s1);
}
static __device__ __forceinline__ float2 score_col50(const float* p, const float* a) {
    float s0 = 0.f, s1 = 0.f;
    #pragma unroll
    for (int f = 0; f < DK; ++f) {
        s0 = fmaf(p[f],      a[25 + f], s0);
        s1 = fmaf(p[DK + f], a[75 + f], s1);
    }
    return make_float2(s0, s1);
}

// ---------------- fac ----------------
struct FacArgs { const float* emb[8]; float* P[8]; const float* Wtk; int base[9]; };

__global__ void fac_kernel(FacArgs A) {
    int g = blockIdx.x * blockDim.x + threadIdx.x;
    if (g >= A.base[8]) return;
    int ty = 0;
    while (g >= A.base[ty + 1]) ++ty;
    int node = g - A.base[ty];
    const float* er = A.emb[ty] + (size_t)node * DD;
    const float* Wt = A.Wtk + (size_t)ty * KF * DD * DK;
    float x[DD];
    #pragma unroll
    for (int d = 0; d < DD; ++d) x[d] = er[d];
    float out[DD];
    #pragma unroll
    for (int k = 0; k < KF; ++k) {
        const float* Wk = Wt + k * DD * DK;
        float nrm = 0.f;
        for (int f = 0; f < DK; ++f) {
            float acc = 0.f;
            for (int d = 0; d < DD; ++d) acc = fmaf(x[d], Wk[d * DK + f], acc);
            acc = leakyf(acc);
            out[k * DK + f] = acc;
            nrm = fmaf(acc, acc, nrm);
        }
        float inv = 1.f / fmaxf(sqrtf(nrm), 1e-12f);
        for (int f = 0; f < DK; ++f) out[k * DK + f] *= inv;
    }
    float* Pr = A.P[ty] + (size_t)node * PS;
    #pragma unroll
    for (int j = 0; j < DD; ++j) Pr[j] = out[j];
    Pr[50] = 0.f; Pr[51] = 0.f;
}

// ---------------- flat CSR build ----------------
struct EdgeArgs {
    const int* rows[8]; const int* cols[8];
    int* cnt;                  // [totalRows] counts -> rowptr (inclusive ends after scatter)
    unsigned short* colind;    // [totE] flat
    int ebase[9];
    int rowbase[8];
};

__global__ void hist_kernel(EdgeArgs A) {
    int g = blockIdx.x * blockDim.x + threadIdx.x;
    if (g >= A.ebase[8]) return;
    int rel = 0;
    while (g >= A.ebase[rel + 1]) ++rel;
    int e = g - A.ebase[rel];
    atomicAdd(&A.cnt[A.rowbase[rel] + A.rows[rel][e]], 1);
}

__global__ __launch_bounds__(1024) void scan_part_kernel(int* a, int n, int* bsum) {
    __shared__ int lds[1024];
    int tid = threadIdx.x;
    int i = blockIdx.x * 1024 + tid;
    int v = (i < n) ? a[i] : 0;
    lds[tid] = v;
    __syncthreads();
    int x = v;
    for (int off = 1; off < 1024; off <<= 1) {
        int y = (tid >= off) ? lds[tid - off] : 0;
        __syncthreads();
        x += y;
        lds[tid] = x;
        __syncthreads();
    }
    if (i < n) a[i] = x - v;
    if (tid == 1023) bsum[blockIdx.x] = x;
}

__global__ __launch_bounds__(1024) void scan_bsum_kernel(int* bsum, int nb) {
    __shared__ int lds[1024];
    int tid = threadIdx.x;
    int v = (tid < nb) ? bsum[tid] : 0;
    lds[tid] = v;
    __syncthreads();
    int x = v;
    for (int off = 1; off < 1024; off <<= 1) {
        int y = (tid >= off) ? lds[tid - off] : 0;
        __syncthreads();
        x += y;
        lds[tid] = x;
        __syncthreads();
    }
    if (tid < nb) bsum[tid] = x - v;
}

__global__ __launch_bounds__(1024) void add_off_kernel(int* a, int n, const int* bsum) {
    int i = blockIdx.x * 1024 + threadIdx.x;
    if (i < n) a[i] += bsum[blockIdx.x];
}

__global__ void scatter_kernel(EdgeArgs A) {
    int g = blockIdx.x * blockDim.x + threadIdx.x;
    if (g >= A.ebase[8]) return;
    int rel = 0;
    while (g >= A.ebase[rel + 1]) ++rel;
    int e = g - A.ebase[rel];
    int p = atomicAdd(&A.cnt[A.rowbase[rel] + A.rows[rel][e]], 1);
    A.colind[p] = (unsigned short)A.cols[rel][e];
}

// ---------------- sb init for static relations 2..7 ----------------
struct SbArgs { const float* Pb[6]; const float* at[6]; float2* sb[6]; int base[7]; };

__global__ void sb_kernel(SbArgs A) {
    int g = blockIdx.x * blockDim.x + threadIdx.x;
    if (g >= A.base[6]) return;
    int rel = 0;
    while (g >= A.base[rel + 1]) ++rel;
    int c = g - A.base[rel];
    const float* p = A.Pb[rel] + (size_t)c * PS;
    A.sb[rel][c] = score_col50(p, A.at[rel]);
}

// ---------------- score01: per-iteration sa (all rels) + sb0/sb1 ----------------
struct ScoreArgs {
    const float* P0; const float* P1;
    const float* at;
    float2* sa[8]; float2* sb0; float2* sb1;
    int n0, n1;
};

__global__ void score01_kernel(ScoreArgs A) {
    int g = blockIdx.x * blockDim.x + threadIdx.x;
    if (g >= A.n0 + A.n1) return;
    if (g < A.n0) {
        const float* p = A.P0 + (size_t)g * PS;
        float pr[DD];
        #pragma unroll
        for (int j = 0; j < DD; ++j) pr[j] = p[j];
        A.sa[0][g] = score_row50(pr, A.at + 0);
        A.sb1[g]   = score_col50(pr, A.at + 100);
    } else {
        int node = g - A.n0;
        const float* p = A.P1 + (size_t)node * PS;
        float pr[DD];
        #pragma unroll
        for (int j = 0; j < DD; ++j) pr[j] = p[j];
        #pragma unroll
        for (int e = 1; e < 8; ++e) A.sa[e][node] = score_row50(pr, A.at + e * 100);
        A.sb0[node] = score_col50(pr, A.at + 0);
    }
}

// ---------------- phase: attention-aggregate only (epilogue moved to ego) ----------------
struct PhaseArgs {
    const int* rowptr;               // [totalRows] inclusive ends (flat)
    const unsigned short* colind;    // flat
    const float* Pb[8];
    const float2* sa[8]; const float2* sb[8];
    float* z[8];                     // z_agg = acc/ssum (raw, pre-leaky)
    int rowbase[9];
};

__global__ __launch_bounds__(WPB * 64) void phase_kernel(PhaseArgs A, int totalRows) {
    int wave = blockIdx.x * WPB + (threadIdx.x >> 6);
    int lane = threadIdx.x & 63;
    if (wave >= totalRows) return;
    int rel = 0;
    while (wave >= A.rowbase[rel + 1]) ++rel;
    int u = wave - A.rowbase[rel];

    const unsigned short* colind = A.colind;
    const float* Pb = A.Pb[rel];
    const float2* sb = A.sb[rel];
    float2 h = A.sa[rel][u];
    int beg = wave ? A.rowptr[wave - 1] : 0;
    int end = A.rowptr[wave];

    bool act = lane < DD;
    int grp4 = lane >> 4, sub4 = lane & 15;
    float ssum = 0.f;
    float4 a4 = make_float4(0.f, 0.f, 0.f, 0.f);

    for (int base = beg; base < end; base += 64) {
        int idx = base + lane;
        bool vld = idx < end;
        int cb = vld ? (int)colind[idx] : 0;
        float evl = 0.f;
        if (vld) {
            float2 sc = sb[cb];
            evl = __expf(0.5f * (fmaxf(h.x + sc.x, 0.f) + fmaxf(h.y + sc.y, 0.f)));
        }
        ssum += evl;
        int nb = min(64, end - base);
        #pragma unroll 4
        for (int t = 0; t < nb; t += 4) {
            int srcl = t + grp4;
            int c = __shfl(cb, srcl);
            float ev = __shfl(evl, srcl);
            const float4* pc = (const float4*)(Pb + (size_t)c * PS);
            float4 v = pc[sub4];
            a4.x = fmaf(ev, v.x, a4.x);
            a4.y = fmaf(ev, v.y, a4.y);
            a4.z = fmaf(ev, v.z, a4.z);
            a4.w = fmaf(ev, v.w, a4.w);
        }
    }
    #pragma unroll
    for (int off = 32; off >= 16; off >>= 1) {
        a4.x += __shfl_xor(a4.x, off);
        a4.y += __shfl_xor(a4.y, off);
        a4.z += __shfl_xor(a4.z, off);
        a4.w += __shfl_xor(a4.w, off);
    }
    #pragma unroll
    for (int off = 32; off; off >>= 1) ssum += __shfl_xor(ssum, off);

    int src = lane >> 2;
    float fx = __shfl(a4.x, src), fy = __shfl(a4.y, src);
    float fz = __shfl(a4.z, src), fw = __shfl(a4.w, src);
    float za = (lane & 1) ? ((lane & 2) ? fw : fy) : ((lane & 2) ? fz : fx);

    float inv = (ssum > 0.f) ? (1.f / ssum) : 0.f;
    if (act) A.z[rel][(size_t)u * DD + lane] = za * inv;
}

// ---------------- ego: per-rel epilogue + combine + l2norm (thread-per-node) ----------------
static __device__ __forceinline__ void epi_rel(const float* zraw, const float* W,
                                               const float* qv, float* o, float2* rr) {
    float zi[DD];
    #pragma unroll
    for (int j = 0; j < DD; ++j) zi[j] = leakyf(zraw[j]);
    float t0 = 0.f, t1 = 0.f;
    #pragma unroll
    for (int k = 0; k < KF; ++k) {
        float tk = 0.f;
        for (int f = 0; f < DK; ++f) {
            float acc = 0.f;
            for (int d = 0; d < DK; ++d) acc = fmaf(zi[k * DK + d], W[d * DK + f], acc);
            o[k * DK + f] = acc;
            tk = fmaf(tanhf(acc), qv[f], tk);
        }
        if (k == 0) t0 = tk; else t1 = tk;
    }
    float m = fmaxf(t0, t1);
    float e0 = __expf(t0 - m), e1 = __expf(t1 - m);
    float rinv = 1.f / (e0 + e1);
    *rr = make_float2(e0 * rinv, e1 * rinv);
}

static __device__ __forceinline__ void l2norm_store(float* dst, const float* acc) {
    #pragma unroll
    for (int k = 0; k < KF; ++k) {
        float nrm = 0.f;
        for (int f = 0; f < DK; ++f) nrm = fmaf(acc[k * DK + f], acc[k * DK + f], nrm);
        float inv = 1.f / fmaxf(sqrtf(nrm), 1e-12f);
        for (int f = 0; f < DK; ++f) dst[k * DK + f] = acc[k * DK + f] * inv;
    }
}

struct EgoArgs {
    float* P0; float* P1;
    const float* zz[8];          // raw z_agg per relation
    const float* W; const float* q;   // q: [8][25]
    int n0, n1;
};

__global__ void ego_kernel(EgoArgs A) {
    int g = blockIdx.x * blockDim.x + threadIdx.x;
    if (g >= A.n0 + A.n1) return;
    float acc[DD], o[DD], zraw[DD];
    float2 rr;
    if (g < A.n0) {
        float* Pr = A.P0 + (size_t)g * PS;
        const float* zr = A.zz[0] + (size_t)g * DD;
        #pragma unroll
        for (int j = 0; j < DD; ++j) zraw[j] = zr[j];
        epi_rel(zraw, A.W, A.q + 0, o, &rr);
        #pragma unroll
        for (int j = 0; j < DD; ++j) acc[j] = fmaf(o[j], (j < DK ? rr.x : rr.y), Pr[j]);
        l2norm_store(Pr, acc);
    } else {
        int node = g - A.n0;
        float* Pr = A.P1 + (size_t)node * PS;
        #pragma unroll
        for (int j = 0; j < DD; ++j) acc[j] = Pr[j];
        for (int e = 1; e < 8; ++e) {
            const float* zr = A.zz[e] + (size_t)node * DD;
            #pragma unroll
            for (int j = 0; j < DD; ++j) zraw[j] = zr[j];
            epi_rel(zraw, A.W, A.q + e * DK, o, &rr);
            #pragma unroll
            for (int j = 0; j < DD; ++j) acc[j] = fmaf(o[j], (j < DK ? rr.x : rr.y), acc[j]);
        }
        l2norm_store(Pr, acc);
    }
}

// ---------------- output: strided copy P(52) -> out(50) ----------------
__global__ void out_kernel(const float* __restrict__ P0, const float* __restrict__ P1,
                           int n0, int n1, float* __restrict__ out) {
    int g = blockIdx.x * blockDim.x + threadIdx.x;
    if (g >= n0 + n1) return;
    const float* src = (g < n0) ? (P0 + (size_t)g * PS) : (P1 + (size_t)(g - n0) * PS);
    float* dst = out + (size_t)g * DD;
    #pragma unroll
    for (int j = 0; j < DD; ++j) dst[j] = src[j];
}

static inline int cdiv(int a, int b) { return (a + b - 1) / b; }

extern "C" void kernel_launch(void* const* d_in, const int* in_sizes, int n_in,
                              void* d_out, int out_size, void* d_ws, size_t ws_size,
                              hipStream_t stream) {
    const int* edge[8];
    int E[8];
    for (int e = 0; e < 8; ++e) { edge[e] = (const int*)d_in[e]; E[e] = in_sizes[e] / 2; }
    const float* emb[8];
    int nn[8];
    for (int i = 0; i < 8; ++i) { emb[i] = (const float*)d_in[8 + i]; nn[i] = in_sizes[8 + i] / DD; }
    const float* Wtk = (const float*)d_in[16];
    const float* at  = (const float*)d_in[17];
    const float* W   = (const float*)d_in[18];
    const float* q   = (const float*)d_in[19];
    float* out = (float*)d_out;

    static const int aIdx[8] = {0, 1, 1, 1, 1, 1, 1, 1};
    static const int bIdx[8] = {1, 0, 2, 3, 4, 5, 6, 7};
    int rows[8], ncol[8];
    for (int e = 0; e < 8; ++e) { rows[e] = nn[aIdx[e]]; ncol[e] = nn[bIdx[e]]; }
    int rowbase[9];
    rowbase[0] = 0;
    for (int e = 0; e < 8; ++e) rowbase[e + 1] = rowbase[e] + rows[e];
    int totalRows = rowbase[8];
    int ebase[9];
    ebase[0] = 0;
    for (int e = 0; e < 8; ++e) ebase[e + 1] = ebase[e] + E[e];
    int totE = ebase[8];

    // ---- workspace: P(52), z, sb, sa, cnt, bsum, colind(u16) ≈ 105 MB ----
    char* w = (char*)d_ws;
    size_t off = 0;
    auto alloc_f  = [&](size_t n) { float*  p = (float*)(w + off);  off += n * 4; return p; };
    auto alloc_f2 = [&](size_t n) { float2* p = (float2*)(w + off); off += n * 8; return p; };
    auto alloc_i  = [&](size_t n) { int*    p = (int*)(w + off);    off += n * 4; return p; };
    float* P[8]; for (int i = 0; i < 8; ++i) P[i] = alloc_f((size_t)nn[i] * PS);
    float* z[8]; for (int e = 0; e < 8; ++e) z[e] = alloc_f((size_t)rows[e] * DD);
    float2* sb[8]; for (int e = 0; e < 8; ++e) sb[e] = alloc_f2((size_t)ncol[e]);
    float2* sa[8]; for (int e = 0; e < 8; ++e) sa[e] = alloc_f2((size_t)rows[e]);
    int* cnt = alloc_i((size_t)totalRows);
    int nchunks = cdiv(totalRows, 1024);
    int* bsum = alloc_i((size_t)nchunks);
    unsigned short* colind = (unsigned short*)(w + off);
    off += (size_t)totE * 2;
    (void)ws_size;

    const int B = 256;

    // ---- flat CSR build ----
    hipMemsetAsync(cnt, 0, (size_t)totalRows * 4, stream);
    EdgeArgs EA;
    for (int e = 0; e < 8; ++e) {
        EA.rows[e] = edge[e]; EA.cols[e] = edge[e] + E[e];
        EA.rowbase[e] = rowbase[e];
        EA.ebase[e] = ebase[e];
    }
    EA.ebase[8] = ebase[8];
    EA.cnt = cnt; EA.colind = colind;
    hist_kernel<<<cdiv(totE, B), B, 0, stream>>>(EA);
    scan_part_kernel<<<nchunks, 1024, 0, stream>>>(cnt, totalRows, bsum);
    scan_bsum_kernel<<<1, 1024, 0, stream>>>(bsum, nchunks);
    add_off_kernel<<<nchunks, 1024, 0, stream>>>(cnt, totalRows, bsum);
    scatter_kernel<<<cdiv(totE, B), B, 0, stream>>>(EA);

    // ---- fac ----
    FacArgs FA;
    FA.base[0] = 0;
    for (int i = 0; i < 8; ++i) { FA.emb[i] = emb[i]; FA.P[i] = P[i]; FA.base[i + 1] = FA.base[i] + nn[i]; }
    FA.Wtk = Wtk;
    fac_kernel<<<cdiv(FA.base[8], B), B, 0, stream>>>(FA);

    // ---- static sb (rels 2..7) once ----
    SbArgs SBs;
    SBs.base[0] = 0;
    for (int e = 2; e < 8; ++e) {
        SBs.Pb[e - 2] = P[bIdx[e]];
        SBs.at[e - 2] = at + (size_t)e * KF * DD;
        SBs.sb[e - 2] = sb[e];
        SBs.base[e - 1] = SBs.base[e - 2] + ncol[e];
    }
    sb_kernel<<<cdiv(SBs.base[6], B), B, 0, stream>>>(SBs);

    // ---- dynamic scores ----
    ScoreArgs SC;
    SC.P0 = P[0]; SC.P1 = P[1]; SC.at = at;
    for (int e = 0; e < 8; ++e) SC.sa[e] = sa[e];
    SC.sb0 = sb[0]; SC.sb1 = sb[1];
    SC.n0 = nn[0]; SC.n1 = nn[1];
    score01_kernel<<<cdiv(nn[0] + nn[1], B), B, 0, stream>>>(SC);

    // ---- iterations ----
    PhaseArgs PA;
    PA.rowptr = cnt; PA.colind = colind;
    for (int e = 0; e < 8; ++e) {
        PA.Pb[e] = P[bIdx[e]];
        PA.sa[e] = sa[e]; PA.sb[e] = sb[e];
        PA.z[e] = z[e];
        PA.rowbase[e] = rowbase[e];
    }
    PA.rowbase[8] = rowbase[8];
    EgoArgs GA;
    GA.P0 = P[0]; GA.P1 = P[1]; GA.n0 = nn[0]; GA.n1 = nn[1];
    for (int e = 0; e < 8; ++e) GA.zz[e] = z[e];
    GA.W = W; GA.q = q;

    for (int it = 0; it < ITERS; ++it) {
        phase_kernel<<<cdiv(totalRows, WPB), WPB * 64, 0, stream>>>(PA, totalRows);
        ego_kernel<<<cdiv(nn[0] + nn[1], B), B, 0, stream>>>(GA);
        score01_kernel<<<cdiv(nn[0] + nn[1], B), B, 0, stream>>>(SC);
    }

    // ---- output ----
    out_kernel<<<cdiv(nn[0] + nn[1], B), B, 0, stream>>>(P[0], P[1], nn[0], nn[1], out);
}

// Round 12
// 3725.333 us; speedup vs baseline: 1.0023x; 1.0023x over previous
//
#include <hip/hip_runtime.h>
#include <math.h>

// GraphEncoder v9 = v8 with the ego scratch-spill fixed: all epi_rel loops
// fully unrolled so zi/o/acc stay in VGPRs (v8's rolled loops -> dynamic
// indexing -> 340 MB scratch traffic, 8% occupancy, 650us ego).
// Phase unchanged from v8 (aggregate-only + unroll-4 t-loop, ~180us).

#define KF 2
#define DK 25
#define DD 50
#define PS 52   // padded P row stride: 208 B = 13 float4
#define ITERS 4
#define WPB 4

static __device__ __forceinline__ float leakyf(float x) { return x > 0.f ? x : 0.2f * x; }

// at[e] is [2][50]: factor k at a+k*50; 0..24 row-side, 25..49 col-side.
static __device__ __forceinline__ float2 score_row50(const float* p, const float* a) {
    float s0 = 0.f, s1 = 0.f;
    #pragma unroll
    for (int f = 0; f < DK; ++f) {
        s0 = fmaf(p[f],      a[f],      s0);
        s1 = fmaf(p[DK + f], a[50 + f], s1);
    }
    return make_float2(s0, s1);
}
static __device__ __forceinline__ float2 score_col50(const float* p, const float* a) {
    float s0 = 0.f, s1 = 0.f;
    #pragma unroll
    for (int f = 0; f < DK; ++f) {
        s0 = fmaf(p[f],      a[25 + f], s0);
        s1 = fmaf(p[DK + f], a[75 + f], s1);
    }
    return make_float2(s0, s1);
}

// ---------------- fac ----------------
struct FacArgs { const float* emb[8]; float* P[8]; const float* Wtk; int base[9]; };

__global__ void fac_kernel(FacArgs A) {
    int g = blockIdx.x * blockDim.x + threadIdx.x;
    if (g >= A.base[8]) return;
    int ty = 0;
    while (g >= A.base[ty + 1]) ++ty;
    int node = g - A.base[ty];
    const float* er = A.emb[ty] + (size_t)node * DD;
    const float* Wt = A.Wtk + (size_t)ty * KF * DD * DK;
    float x[DD];
    #pragma unroll
    for (int d = 0; d < DD; ++d) x[d] = er[d];
    float out[DD];
    #pragma unroll
    for (int k = 0; k < KF; ++k) {
        const float* Wk = Wt + k * DD * DK;
        float nrm = 0.f;
        #pragma unroll
        for (int f = 0; f < DK; ++f) {
            float acc = 0.f;
            #pragma unroll
            for (int d = 0; d < DD; ++d) acc = fmaf(x[d], Wk[d * DK + f], acc);
            acc = leakyf(acc);
            out[k * DK + f] = acc;
            nrm = fmaf(acc, acc, nrm);
        }
        float inv = 1.f / fmaxf(sqrtf(nrm), 1e-12f);
        #pragma unroll
        for (int f = 0; f < DK; ++f) out[k * DK + f] *= inv;
    }
    float* Pr = A.P[ty] + (size_t)node * PS;
    #pragma unroll
    for (int j = 0; j < DD; ++j) Pr[j] = out[j];
    Pr[50] = 0.f; Pr[51] = 0.f;
}

// ---------------- flat CSR build ----------------
struct EdgeArgs {
    const int* rows[8]; const int* cols[8];
    int* cnt;
    unsigned short* colind;
    int ebase[9];
    int rowbase[8];
};

__global__ void hist_kernel(EdgeArgs A) {
    int g = blockIdx.x * blockDim.x + threadIdx.x;
    if (g >= A.ebase[8]) return;
    int rel = 0;
    while (g >= A.ebase[rel + 1]) ++rel;
    int e = g - A.ebase[rel];
    atomicAdd(&A.cnt[A.rowbase[rel] + A.rows[rel][e]], 1);
}

__global__ __launch_bounds__(1024) void scan_part_kernel(int* a, int n, int* bsum) {
    __shared__ int lds[1024];
    int tid = threadIdx.x;
    int i = blockIdx.x * 1024 + tid;
    int v = (i < n) ? a[i] : 0;
    lds[tid] = v;
    __syncthreads();
    int x = v;
    for (int off = 1; off < 1024; off <<= 1) {
        int y = (tid >= off) ? lds[tid - off] : 0;
        __syncthreads();
        x += y;
        lds[tid] = x;
        __syncthreads();
    }
    if (i < n) a[i] = x - v;
    if (tid == 1023) bsum[blockIdx.x] = x;
}

__global__ __launch_bounds__(1024) void scan_bsum_kernel(int* bsum, int nb) {
    __shared__ int lds[1024];
    int tid = threadIdx.x;
    int v = (tid < nb) ? bsum[tid] : 0;
    lds[tid] = v;
    __syncthreads();
    int x = v;
    for (int off = 1; off < 1024; off <<= 1) {
        int y = (tid >= off) ? lds[tid - off] : 0;
        __syncthreads();
        x += y;
        lds[tid] = x;
        __syncthreads();
    }
    if (tid < nb) bsum[tid] = x - v;
}

__global__ __launch_bounds__(1024) void add_off_kernel(int* a, int n, const int* bsum) {
    int i = blockIdx.x * 1024 + threadIdx.x;
    if (i < n) a[i] += bsum[blockIdx.x];
}

__global__ void scatter_kernel(EdgeArgs A) {
    int g = blockIdx.x * blockDim.x + threadIdx.x;
    if (g >= A.ebase[8]) return;
    int rel = 0;
    while (g >= A.ebase[rel + 1]) ++rel;
    int e = g - A.ebase[rel];
    int p = atomicAdd(&A.cnt[A.rowbase[rel] + A.rows[rel][e]], 1);
    A.colind[p] = (unsigned short)A.cols[rel][e];
}

// ---------------- sb init for static relations 2..7 ----------------
struct SbArgs { const float* Pb[6]; const float* at[6]; float2* sb[6]; int base[7]; };

__global__ void sb_kernel(SbArgs A) {
    int g = blockIdx.x * blockDim.x + threadIdx.x;
    if (g >= A.base[6]) return;
    int rel = 0;
    while (g >= A.base[rel + 1]) ++rel;
    int c = g - A.base[rel];
    const float* p = A.Pb[rel] + (size_t)c * PS;
    A.sb[rel][c] = score_col50(p, A.at[rel]);
}

// ---------------- score01 ----------------
struct ScoreArgs {
    const float* P0; const float* P1;
    const float* at;
    float2* sa[8]; float2* sb0; float2* sb1;
    int n0, n1;
};

__global__ void score01_kernel(ScoreArgs A) {
    int g = blockIdx.x * blockDim.x + threadIdx.x;
    if (g >= A.n0 + A.n1) return;
    if (g < A.n0) {
        const float* p = A.P0 + (size_t)g * PS;
        float pr[DD];
        #pragma unroll
        for (int j = 0; j < DD; ++j) pr[j] = p[j];
        A.sa[0][g] = score_row50(pr, A.at + 0);
        A.sb1[g]   = score_col50(pr, A.at + 100);
    } else {
        int node = g - A.n0;
        const float* p = A.P1 + (size_t)node * PS;
        float pr[DD];
        #pragma unroll
        for (int j = 0; j < DD; ++j) pr[j] = p[j];
        #pragma unroll
        for (int e = 1; e < 8; ++e) A.sa[e][node] = score_row50(pr, A.at + e * 100);
        A.sb0[node] = score_col50(pr, A.at + 0);
    }
}

// ---------------- phase: attention-aggregate only ----------------
struct PhaseArgs {
    const int* rowptr;
    const unsigned short* colind;
    const float* Pb[8];
    const float2* sa[8]; const float2* sb[8];
    float* z[8];
    int rowbase[9];
};

__global__ __launch_bounds__(WPB * 64) void phase_kernel(PhaseArgs A, int totalRows) {
    int wave = blockIdx.x * WPB + (threadIdx.x >> 6);
    int lane = threadIdx.x & 63;
    if (wave >= totalRows) return;
    int rel = 0;
    while (wave >= A.rowbase[rel + 1]) ++rel;
    int u = wave - A.rowbase[rel];

    const unsigned short* colind = A.colind;
    const float* Pb = A.Pb[rel];
    const float2* sb = A.sb[rel];
    float2 h = A.sa[rel][u];
    int beg = wave ? A.rowptr[wave - 1] : 0;
    int end = A.rowptr[wave];

    bool act = lane < DD;
    int grp4 = lane >> 4, sub4 = lane & 15;
    float ssum = 0.f;
    float4 a4 = make_float4(0.f, 0.f, 0.f, 0.f);

    for (int base = beg; base < end; base += 64) {
        int idx = base + lane;
        bool vld = idx < end;
        int cb = vld ? (int)colind[idx] : 0;
        float evl = 0.f;
        if (vld) {
            float2 sc = sb[cb];
            evl = __expf(0.5f * (fmaxf(h.x + sc.x, 0.f) + fmaxf(h.y + sc.y, 0.f)));
        }
        ssum += evl;
        int nb = min(64, end - base);
        #pragma unroll 4
        for (int t = 0; t < nb; t += 4) {
            int srcl = t + grp4;
            int c = __shfl(cb, srcl);
            float ev = __shfl(evl, srcl);
            const float4* pc = (const float4*)(Pb + (size_t)c * PS);
            float4 v = pc[sub4];
            a4.x = fmaf(ev, v.x, a4.x);
            a4.y = fmaf(ev, v.y, a4.y);
            a4.z = fmaf(ev, v.z, a4.z);
            a4.w = fmaf(ev, v.w, a4.w);
        }
    }
    #pragma unroll
    for (int off = 32; off >= 16; off >>= 1) {
        a4.x += __shfl_xor(a4.x, off);
        a4.y += __shfl_xor(a4.y, off);
        a4.z += __shfl_xor(a4.z, off);
        a4.w += __shfl_xor(a4.w, off);
    }
    #pragma unroll
    for (int off = 32; off; off >>= 1) ssum += __shfl_xor(ssum, off);

    int src = lane >> 2;
    float fx = __shfl(a4.x, src), fy = __shfl(a4.y, src);
    float fz = __shfl(a4.z, src), fw = __shfl(a4.w, src);
    float za = (lane & 1) ? ((lane & 2) ? fw : fy) : ((lane & 2) ? fz : fx);

    float inv = (ssum > 0.f) ? (1.f / ssum) : 0.f;
    if (act) A.z[rel][(size_t)u * DD + lane] = za * inv;
}

// ---------------- ego: epilogue + combine + l2norm, all loops UNROLLED ----------------
static __device__ __forceinline__ void epi_rel(const float* __restrict__ zr,
                                               const float* __restrict__ W,
                                               const float* __restrict__ qv,
                                               float* __restrict__ o, float2* rr) {
    float zi[DD];
    #pragma unroll
    for (int j = 0; j < DD; ++j) zi[j] = leakyf(zr[j]);
    float t0 = 0.f, t1 = 0.f;
    #pragma unroll
    for (int k = 0; k < KF; ++k) {
        float tk = 0.f;
        #pragma unroll
        for (int f = 0; f < DK; ++f) {
            float acc = 0.f;
            #pragma unroll
            for (int d = 0; d < DK; ++d) acc = fmaf(zi[k * DK + d], W[d * DK + f], acc);
            o[k * DK + f] = acc;
            tk = fmaf(tanhf(acc), qv[f], tk);
        }
        if (k == 0) t0 = tk; else t1 = tk;
    }
    float m = fmaxf(t0, t1);
    float e0 = __expf(t0 - m), e1 = __expf(t1 - m);
    float rinv = 1.f / (e0 + e1);
    *rr = make_float2(e0 * rinv, e1 * rinv);
}

static __device__ __forceinline__ void l2norm_store(float* dst, const float* acc) {
    #pragma unroll
    for (int k = 0; k < KF; ++k) {
        float nrm = 0.f;
        #pragma unroll
        for (int f = 0; f < DK; ++f) nrm = fmaf(acc[k * DK + f], acc[k * DK + f], nrm);
        float inv = 1.f / fmaxf(sqrtf(nrm), 1e-12f);
        #pragma unroll
        for (int f = 0; f < DK; ++f) dst[k * DK + f] = acc[k * DK + f] * inv;
    }
}

struct EgoArgs {
    float* P0; float* P1;
    const float* zz[8];
    const float* W; const float* q;
    int n0, n1;
};

__global__ void ego_kernel(EgoArgs A) {
    int g = blockIdx.x * blockDim.x + threadIdx.x;
    if (g >= A.n0 + A.n1) return;
    float acc[DD], o[DD];
    float2 rr;
    if (g < A.n0) {
        float* Pr = A.P0 + (size_t)g * PS;
        epi_rel(A.zz[0] + (size_t)g * DD, A.W, A.q + 0, o, &rr);
        #pragma unroll
        for (int j = 0; j < DD; ++j) acc[j] = fmaf(o[j], (j < DK ? rr.x : rr.y), Pr[j]);
        l2norm_store(Pr, acc);
    } else {
        int node = g - A.n0;
        float* Pr = A.P1 + (size_t)node * PS;
        #pragma unroll
        for (int j = 0; j < DD; ++j) acc[j] = Pr[j];
        for (int e = 1; e < 8; ++e) {   // rolled: bounds code size; arrays stay in regs
            epi_rel(A.zz[e] + (size_t)node * DD, A.W, A.q + e * DK, o, &rr);
            #pragma unroll
            for (int j = 0; j < DD; ++j) acc[j] = fmaf(o[j], (j < DK ? rr.x : rr.y), acc[j]);
        }
        l2norm_store(Pr, acc);
    }
}

// ---------------- output: strided copy P(52) -> out(50) ----------------
__global__ void out_kernel(const float* __restrict__ P0, const float* __restrict__ P1,
                           int n0, int n1, float* __restrict__ out) {
    int g = blockIdx.x * blockDim.x + threadIdx.x;
    if (g >= n0 + n1) return;
    const float* src = (g < n0) ? (P0 + (size_t)g * PS) : (P1 + (size_t)(g - n0) * PS);
    float* dst = out + (size_t)g * DD;
    #pragma unroll
    for (int j = 0; j < DD; ++j) dst[j] = src[j];
}

static inline int cdiv(int a, int b) { return (a + b - 1) / b; }

extern "C" void kernel_launch(void* const* d_in, const int* in_sizes, int n_in,
                              void* d_out, int out_size, void* d_ws, size_t ws_size,
                              hipStream_t stream) {
    const int* edge[8];
    int E[8];
    for (int e = 0; e < 8; ++e) { edge[e] = (const int*)d_in[e]; E[e] = in_sizes[e] / 2; }
    const float* emb[8];
    int nn[8];
    for (int i = 0; i < 8; ++i) { emb[i] = (const float*)d_in[8 + i]; nn[i] = in_sizes[8 + i] / DD; }
    const float* Wtk = (const float*)d_in[16];
    const float* at  = (const float*)d_in[17];
    const float* W   = (const float*)d_in[18];
    const float* q   = (const float*)d_in[19];
    float* out = (float*)d_out;

    static const int aIdx[8] = {0, 1, 1, 1, 1, 1, 1, 1};
    static const int bIdx[8] = {1, 0, 2, 3, 4, 5, 6, 7};
    int rows[8], ncol[8];
    for (int e = 0; e < 8; ++e) { rows[e] = nn[aIdx[e]]; ncol[e] = nn[bIdx[e]]; }
    int rowbase[9];
    rowbase[0] = 0;
    for (int e = 0; e < 8; ++e) rowbase[e + 1] = rowbase[e] + rows[e];
    int totalRows = rowbase[8];
    int ebase[9];
    ebase[0] = 0;
    for (int e = 0; e < 8; ++e) ebase[e + 1] = ebase[e] + E[e];
    int totE = ebase[8];

    // ---- workspace ≈ 105 MB ----
    char* w = (char*)d_ws;
    size_t off = 0;
    auto alloc_f  = [&](size_t n) { float*  p = (float*)(w + off);  off += n * 4; return p; };
    auto alloc_f2 = [&](size_t n) { float2* p = (float2*)(w + off); off += n * 8; return p; };
    auto alloc_i  = [&](size_t n) { int*    p = (int*)(w + off);    off += n * 4; return p; };
    float* P[8]; for (int i = 0; i < 8; ++i) P[i] = alloc_f((size_t)nn[i] * PS);
    float* z[8]; for (int e = 0; e < 8; ++e) z[e] = alloc_f((size_t)rows[e] * DD);
    float2* sb[8]; for (int e = 0; e < 8; ++e) sb[e] = alloc_f2((size_t)ncol[e]);
    float2* sa[8]; for (int e = 0; e < 8; ++e) sa[e] = alloc_f2((size_t)rows[e]);
    int* cnt = alloc_i((size_t)totalRows);
    int nchunks = cdiv(totalRows, 1024);
    int* bsum = alloc_i((size_t)nchunks);
    unsigned short* colind = (unsigned short*)(w + off);
    off += (size_t)totE * 2;
    (void)ws_size;

    const int B = 256;

    // ---- flat CSR build ----
    hipMemsetAsync(cnt, 0, (size_t)totalRows * 4, stream);
    EdgeArgs EA;
    for (int e = 0; e < 8; ++e) {
        EA.rows[e] = edge[e]; EA.cols[e] = edge[e] + E[e];
        EA.rowbase[e] = rowbase[e];
        EA.ebase[e] = ebase[e];
    }
    EA.ebase[8] = ebase[8];
    EA.cnt = cnt; EA.colind = colind;
    hist_kernel<<<cdiv(totE, B), B, 0, stream>>>(EA);
    scan_part_kernel<<<nchunks, 1024, 0, stream>>>(cnt, totalRows, bsum);
    scan_bsum_kernel<<<1, 1024, 0, stream>>>(bsum, nchunks);
    add_off_kernel<<<nchunks, 1024, 0, stream>>>(cnt, totalRows, bsum);
    scatter_kernel<<<cdiv(totE, B), B, 0, stream>>>(EA);

    // ---- fac ----
    FacArgs FA;
    FA.base[0] = 0;
    for (int i = 0; i < 8; ++i) { FA.emb[i] = emb[i]; FA.P[i] = P[i]; FA.base[i + 1] = FA.base[i] + nn[i]; }
    FA.Wtk = Wtk;
    fac_kernel<<<cdiv(FA.base[8], B), B, 0, stream>>>(FA);

    // ---- static sb (rels 2..7) once ----
    SbArgs SBs;
    SBs.base[0] = 0;
    for (int e = 2; e < 8; ++e) {
        SBs.Pb[e - 2] = P[bIdx[e]];
        SBs.at[e - 2] = at + (size_t)e * KF * DD;
        SBs.sb[e - 2] = sb[e];
        SBs.base[e - 1] = SBs.base[e - 2] + ncol[e];
    }
    sb_kernel<<<cdiv(SBs.base[6], B), B, 0, stream>>>(SBs);

    // ---- dynamic scores ----
    ScoreArgs SC;
    SC.P0 = P[0]; SC.P1 = P[1]; SC.at = at;
    for (int e = 0; e < 8; ++e) SC.sa[e] = sa[e];
    SC.sb0 = sb[0]; SC.sb1 = sb[1];
    SC.n0 = nn[0]; SC.n1 = nn[1];
    score01_kernel<<<cdiv(nn[0] + nn[1], B), B, 0, stream>>>(SC);

    // ---- iterations ----
    PhaseArgs PA;
    PA.rowptr = cnt; PA.colind = colind;
    for (int e = 0; e < 8; ++e) {
        PA.Pb[e] = P[bIdx[e]];
        PA.sa[e] = sa[e]; PA.sb[e] = sb[e];
        PA.z[e] = z[e];
        PA.rowbase[e] = rowbase[e];
    }
    PA.rowbase[8] = rowbase[8];
    EgoArgs GA;
    GA.P0 = P[0]; GA.P1 = P[1]; GA.n0 = nn[0]; GA.n1 = nn[1];
    for (int e = 0; e < 8; ++e) GA.zz[e] = z[e];
    GA.W = W; GA.q = q;

    for (int it = 0; it < ITERS; ++it) {
        phase_kernel<<<cdiv(totalRows, WPB), WPB * 64, 0, stream>>>(PA, totalRows);
        ego_kernel<<<cdiv(nn[0] + nn[1], B), B, 0, stream>>>(GA);
        score01_kernel<<<cdiv(nn[0] + nn[1], B), B, 0, stream>>>(SC);
    }

    // ---- output ----
    out_kernel<<<cdiv(nn[0] + nn[1], B), B, 0, stream>>>(P[0], P[1], nn[0], nn[1], out);
}